// Round 1
// baseline (1444.761 us; speedup 1.0000x reference)
//
#include <hip/hip_runtime.h>
#include <hip/hip_bf16.h>
#include <math.h>

#define NB 2048
#define NT 64
#define ND 512
#define NS 64
#define NTHREADS 512
#define LN_EPS 1e-5f

// dynamic LDS layout (float offsets)
//  xh   [0, 32768)      : f32 [64][512] hidden tile
//  dec  [32768, 36864)  : f32 [64][64] decay; aliases WdL[32][64]+WbL[32][64] staging and WcL[64][64] staging
//  drvH (bytes 147456..): bf16 [64][64] drive -> hs
//  hT   [38912, 38976)  : f32 [64]
//  stm  [38976, 39488)  : f32 [512] shot-term
//  red  [39488, 39506)  : f32 [18] LN reduction
#define XH_OFF    0
#define DEC_OFF   32768
#define DRV_OFFB  147456
#define HT_OFF    38912
#define ST_OFF    38976
#define RED_OFF   39488
#define LDS_FLOATS 39506
#define LDS_BYTES  ((size_t)LDS_FLOATS * 4)

__global__ __launch_bounds__(NTHREADS)
void ssm_fused(const float* __restrict__ tokens, const float* __restrict__ pos_emb,
               const float* __restrict__ A_log,
               const float* __restrict__ Wd, const float* __restrict__ bd,
               const float* __restrict__ Wb, const float* __restrict__ bb,
               const float* __restrict__ Wc, const float* __restrict__ bc,
               const float* __restrict__ Dp,
               const float* __restrict__ Ws, const float* __restrict__ bs,
               const float* __restrict__ gma, const float* __restrict__ bta,
               float* __restrict__ out_hidden, float* __restrict__ out_shot)
{
    extern __shared__ float lds[];
    float* xh  = lds + XH_OFF;
    float* dec = lds + DEC_OFF;
    __hip_bfloat16* drvH = (__hip_bfloat16*)((char*)lds + DRV_OFFB);
    float* hT  = lds + HT_OFF;
    float* stm = lds + ST_OFF;
    float* red = lds + RED_OFF;

    const int tid = threadIdx.x;
    const int b   = blockIdx.x;

    // ---- hidden = tokens[b] + pos_emb ----
    {
        const float4* tp = (const float4*)(tokens + (size_t)b * (NT * ND));
        const float4* pp = (const float4*)pos_emb;   // [64][512] == full tile, same flat layout
        float4* xp = (float4*)xh;
        #pragma unroll
        for (int r = 0; r < 16; ++r) {
            int f = tid + r * NTHREADS;
            float4 a = tp[f], p = pp[f];
            a.x += p.x; a.y += p.y; a.z += p.z; a.w += p.w;
            xp[f] = a;
        }
    }
    __syncthreads();

    for (int dep = 0; dep < 2; ++dep) {
        const float* Wd_d = Wd + dep * ND * NS;   // [512][64]
        const float* Wb_d = Wb + dep * ND * NS;
        const float* bd_d = bd + dep * NS;
        const float* bb_d = bb + dep * NS;
        const float* Al_d = A_log + dep * NS;
        const float* Wc_d = Wc + dep * NS * ND;   // [64][512]
        const float* bc_d = bc + dep * ND;
        const float* Dp_d = Dp + dep * ND;
        const float* Ws_d = Ws + dep * NS * ND;   // [64][512]
        const float* bs_d = bs + dep * ND;

        // ================= phase A: delta/decay/drive =================
        // thread tile: 2 t x 4 s
        const int t0 = (tid >> 4) * 2;
        const int s0 = (tid & 15) * 4;
        float accD[2][4] = {{0.f,0.f,0.f,0.f},{0.f,0.f,0.f,0.f}};
        float accB[2][4] = {{0.f,0.f,0.f,0.f},{0.f,0.f,0.f,0.f}};

        for (int kb = 0; kb < 16; ++kb) {
            // stage WdL [32][64] into dec[0..2047], WbL into dec[2048..4095]
            ((float4*)dec)[tid]            = ((const float4*)(Wd_d + kb * 2048))[tid];
            ((float4*)dec)[NTHREADS + tid] = ((const float4*)(Wb_d + kb * 2048))[tid];
            __syncthreads();
            const float* WdL = dec;
            const float* WbL = dec + 2048;
            #pragma unroll 8
            for (int k = 0; k < 32; ++k) {
                float x0 = xh[t0 * ND + kb * 32 + k];
                float x1 = xh[(t0 + 1) * ND + kb * 32 + k];
                float4 wd4 = *(const float4*)&WdL[k * 64 + s0];
                float4 wb4 = *(const float4*)&WbL[k * 64 + s0];
                accD[0][0] = fmaf(x0, wd4.x, accD[0][0]);
                accD[0][1] = fmaf(x0, wd4.y, accD[0][1]);
                accD[0][2] = fmaf(x0, wd4.z, accD[0][2]);
                accD[0][3] = fmaf(x0, wd4.w, accD[0][3]);
                accD[1][0] = fmaf(x1, wd4.x, accD[1][0]);
                accD[1][1] = fmaf(x1, wd4.y, accD[1][1]);
                accD[1][2] = fmaf(x1, wd4.z, accD[1][2]);
                accD[1][3] = fmaf(x1, wd4.w, accD[1][3]);
                accB[0][0] = fmaf(x0, wb4.x, accB[0][0]);
                accB[0][1] = fmaf(x0, wb4.y, accB[0][1]);
                accB[0][2] = fmaf(x0, wb4.z, accB[0][2]);
                accB[0][3] = fmaf(x0, wb4.w, accB[0][3]);
                accB[1][0] = fmaf(x1, wb4.x, accB[1][0]);
                accB[1][1] = fmaf(x1, wb4.y, accB[1][1]);
                accB[1][2] = fmaf(x1, wb4.z, accB[1][2]);
                accB[1][3] = fmaf(x1, wb4.w, accB[1][3]);
            }
            __syncthreads();
        }

        // elementwise: softplus -> decay/drive; store decay f32, drive bf16
        #pragma unroll
        for (int j = 0; j < 2; ++j) {
            int t = t0 + j;
            #pragma unroll
            for (int i = 0; i < 4; ++i) {
                int s = s0 + i;
                float sp = accD[j][i] + bd_d[s];
                float delta = (sp > 20.f) ? sp : log1pf(__expf(sp));
                float dcy = __expf(-delta * __expf(Al_d[s]));
                float drv = delta * (accB[j][i] + bb_d[s]);
                dec[t * 64 + s]  = dcy;
                drvH[t * 64 + s] = __float2bfloat16(drv);
            }
        }
        __syncthreads();

        // ================= scan over T (8 chunks x 8 steps) =================
        {
            const int s = tid & 63, w = tid >> 6;
            float h = 0.f, p = 1.f;
            float hlv[8], plv[8];
            #pragma unroll
            for (int i = 0; i < 8; ++i) {
                int t = w * 8 + i;
                float dcy = dec[t * 64 + s];
                float u = __bfloat162float(drvH[t * 64 + s]);
                h = fmaf(dcy, h, u);
                p *= dcy;
                hlv[i] = h; plv[i] = p;
            }
            // publish F_w, P_w (only this thread ever touched dec[t][s] for its rows)
            dec[(w * 8 + 6) * 64 + s] = h;
            dec[(w * 8 + 7) * 64 + s] = p;
            __syncthreads();
            float hin = 0.f;
            for (int j = 0; j < w; ++j)
                hin = fmaf(dec[(j * 8 + 7) * 64 + s], hin, dec[(j * 8 + 6) * 64 + s]);
            #pragma unroll
            for (int i = 0; i < 8; ++i) {
                float hf = fmaf(hin, plv[i], hlv[i]);
                drvH[(w * 8 + i) * 64 + s] = __float2bfloat16(hf);   // hs
                if (w == 7 && i == 7) hT[s] = hf;                    // final state
            }
        }
        __syncthreads();

        // ================= shot-term: hT @ Ws + bs =================
        {
            float acc = bs_d[tid];
            #pragma unroll 8
            for (int s = 0; s < 64; ++s)
                acc = fmaf(hT[s], Ws_d[s * ND + tid], acc);
            stm[tid] = acc;
        }
        __syncthreads();

        // ================= phase C: hidden = hs@Wc + bc + x*Dp + stm =================
        const int tc = (tid >> 4) * 2;
        const int d0 = (tid & 15) * 4;
        for (int dc = 0; dc < 8; ++dc) {
            // stage WcL [64 s][64 d] into dec
            #pragma unroll
            for (int r = 0; r < 2; ++r) {
                int f = tid + r * NTHREADS;       // float4 index
                int srow = f >> 4, j4 = f & 15;
                ((float4*)dec)[f] = *(const float4*)&Wc_d[srow * ND + dc * 64 + j4 * 4];
            }
            __syncthreads();
            float acc[2][4] = {{0.f,0.f,0.f,0.f},{0.f,0.f,0.f,0.f}};
            #pragma unroll 4
            for (int s = 0; s < 64; ++s) {
                float h0 = __bfloat162float(drvH[tc * 64 + s]);
                float h1 = __bfloat162float(drvH[(tc + 1) * 64 + s]);
                float4 w4 = *(const float4*)&dec[s * 64 + d0];
                acc[0][0] = fmaf(h0, w4.x, acc[0][0]);
                acc[0][1] = fmaf(h0, w4.y, acc[0][1]);
                acc[0][2] = fmaf(h0, w4.z, acc[0][2]);
                acc[0][3] = fmaf(h0, w4.w, acc[0][3]);
                acc[1][0] = fmaf(h1, w4.x, acc[1][0]);
                acc[1][1] = fmaf(h1, w4.y, acc[1][1]);
                acc[1][2] = fmaf(h1, w4.z, acc[1][2]);
                acc[1][3] = fmaf(h1, w4.w, acc[1][3]);
            }
            #pragma unroll
            for (int j = 0; j < 2; ++j) {
                int t = tc + j;
                #pragma unroll
                for (int i = 0; i < 4; ++i) {
                    int d = dc * 64 + d0 + i;
                    float v = acc[j][i] + bc_d[d] + xh[t * ND + d] * Dp_d[d] + stm[d];
                    xh[t * ND + d] = v;   // only the owning thread reads/writes this element
                }
            }
            __syncthreads();
        }
    } // depth

    // ================= pooled + LayerNorm =================
    float accp = 0.f;
    #pragma unroll 8
    for (int t = 0; t < NT; ++t) accp += xh[t * ND + tid];
    float pooled = accp * (1.0f / NT) + stm[tid];   // stm holds last depth's term = Ws[-1] term

    float s1 = pooled, s2 = pooled * pooled;
    #pragma unroll
    for (int off = 32; off; off >>= 1) {
        s1 += __shfl_down(s1, off, 64);
        s2 += __shfl_down(s2, off, 64);
    }
    const int lane = tid & 63, wv = tid >> 6;
    if (lane == 0) { red[wv] = s1; red[8 + wv] = s2; }
    __syncthreads();
    if (tid == 0) {
        float a = 0.f, q = 0.f;
        for (int w = 0; w < 8; ++w) { a += red[w]; q += red[8 + w]; }
        float mu = a * (1.0f / ND);
        float var = q * (1.0f / ND) - mu * mu;
        red[16] = mu;
        red[17] = rsqrtf(var + LN_EPS);
    }
    __syncthreads();
    float sh = (pooled - red[16]) * red[17] * gma[tid] + bta[tid];
    out_shot[(size_t)b * ND + tid] = sh;

    // write hidden
    {
        const float4* xp = (const float4*)xh;
        float4* op = (float4*)(out_hidden + (size_t)b * (NT * ND));
        #pragma unroll
        for (int r = 0; r < 16; ++r) {
            int f = tid + r * NTHREADS;
            op[f] = xp[f];
        }
    }
}

extern "C" void kernel_launch(void* const* d_in, const int* in_sizes, int n_in,
                              void* d_out, int out_size, void* d_ws, size_t ws_size,
                              hipStream_t stream) {
    const float* tokens  = (const float*)d_in[0];
    const float* pos_emb = (const float*)d_in[1];
    const float* A_log   = (const float*)d_in[2];
    const float* Wd      = (const float*)d_in[3];
    const float* bd      = (const float*)d_in[4];
    const float* Wb      = (const float*)d_in[5];
    const float* bb      = (const float*)d_in[6];
    const float* Wc      = (const float*)d_in[7];
    const float* bc      = (const float*)d_in[8];
    const float* Dp      = (const float*)d_in[9];
    const float* Ws      = (const float*)d_in[10];
    const float* bs      = (const float*)d_in[11];
    const float* gma     = (const float*)d_in[12];
    const float* bta     = (const float*)d_in[13];

    float* out_hidden = (float*)d_out;
    float* out_shot   = (float*)d_out + (size_t)NB * NT * ND;

    // allow >64KB dynamic LDS (158024 B <= 160 KiB/CU)
    hipFuncSetAttribute((const void*)ssm_fused,
                        hipFuncAttributeMaxDynamicSharedMemorySize,
                        (int)LDS_BYTES);

    ssm_fused<<<NB, NTHREADS, LDS_BYTES, stream>>>(
        tokens, pos_emb, A_log, Wd, bd, Wb, bb, Wc, bc, Dp, Ws, bs, gma, bta,
        out_hidden, out_shot);
}

// Round 2
// 632.837 us; speedup vs baseline: 2.2830x; 2.2830x over previous
//
#include <hip/hip_runtime.h>
#include <hip/hip_bf16.h>
#include <math.h>

typedef __attribute__((ext_vector_type(8))) short bf16x8;
typedef __attribute__((ext_vector_type(4))) float f32x4;

#define NB 2048
#define NT 64
#define ND 512
#define NS 64
#define NTH 512
#define LN_EPS 1e-5f

// ---- LDS layout (bytes) ----
#define XH_B    0        // bf16 [64][512] swizzled  (65536 B)
#define HS_B    65536    // bf16 [64][64]  swizzled  (8192 B)
#define SCANF_B 73728    // f32  [64] wave0 scan totals (256 B used, 1024 reserved)
#define HT_B    74752    // f32  [64]
#define STM_B   75008    // f32  [512]
#define RED_B   77056    // f32  [32]
#define LDS_BYTES 77184

// ws (ushort elements): BdPack [2][4][16][64][8] @0 ; BbPack @65536 ; BcPack [2][32][2][64][8] @131072
#define BB_OFF 65536
#define BC_OFF 131072
#define PACK_ELEMS 196608

__device__ __forceinline__ unsigned short f2b(float x) {
    __hip_bfloat16 h = __float2bfloat16(x);
    return *(unsigned short*)&h;
}
__device__ __forceinline__ float b2f(unsigned short u) {
    __hip_bfloat16 h; *(unsigned short*)&h = u;
    return __bfloat162float(h);
}
// swizzled byte offsets
__device__ __forceinline__ int xh_off(int t, int cb) { return t * 1024 + (cb ^ ((t & 15) << 4)); }
__device__ __forceinline__ int hs_off(int t, int cb) { return t * 128  + (cb ^ ((t & 7)  << 4)); }

// ---------------- prep: pack weights to bf16 in MFMA B-fragment order ----------------
__global__ void prep_pack(const float* __restrict__ Wd, const float* __restrict__ Wb,
                          const float* __restrict__ Wc, unsigned short* __restrict__ pack) {
    int i = blockIdx.x * 256 + threadIdx.x;
    if (i >= PACK_ELEMS) return;
    int which = i >> 16;          // 0=Bd 1=Bb 2=Bc
    int r = i & 0xFFFF;
    float v;
    if (which < 2) {
        int j = r & 7, l = (r >> 3) & 63, ks = (r >> 9) & 15, nt = (r >> 13) & 3, dep = r >> 15;
        int s = nt * 16 + (l & 15);
        int k = ks * 32 + (l >> 4) * 8 + j;
        const float* W = which ? Wb : Wd;
        v = W[(dep * 512 + k) * 64 + s];
    } else {
        int j = r & 7, l = (r >> 3) & 63, ks = (r >> 9) & 1, ntg = (r >> 10) & 31, dep = r >> 15;
        int d = ntg * 16 + (l & 15);
        int k = ks * 32 + (l >> 4) * 8 + j;
        v = Wc[(dep * 64 + k) * 512 + d];
    }
    pack[i] = f2b(v);
}

// ---------------- main fused kernel: 1 block per batch element ----------------
__global__ __launch_bounds__(NTH, 4)
void ssm_mfma(const float* __restrict__ tokens, const float* __restrict__ pos_emb,
              const float* __restrict__ A_log,
              const float* __restrict__ bd, const float* __restrict__ bb,
              const float* __restrict__ bc, const float* __restrict__ Dp,
              const float* __restrict__ Ws, const float* __restrict__ bs,
              const float* __restrict__ gma, const float* __restrict__ bta,
              const unsigned short* __restrict__ pack,
              float* __restrict__ out_hidden, float* __restrict__ out_shot)
{
    extern __shared__ char sm[];
    float* scanF = (float*)(sm + SCANF_B);
    float* hT    = (float*)(sm + HT_B);
    float* stm   = (float*)(sm + STM_B);
    float* red   = (float*)(sm + RED_B);

    const int tid  = threadIdx.x;
    const int b    = blockIdx.x;
    const int lane = tid & 63;
    const int w    = tid >> 6;
    const int lr   = lane & 15;
    const int lg   = lane >> 4;
    const int nt   = w & 3;      // phase-A N-tile (s)
    const int mh   = w >> 2;     // phase-A M-half (t 32*mh..+32)

    // ---- stage tokens + pos_emb -> bf16 swizzled xh ----
    {
        const float4* tp = (const float4*)(tokens + (size_t)b * (NT * ND));
        const float4* pp = (const float4*)pos_emb;
        #pragma unroll
        for (int i = 0; i < 16; ++i) {
            int f = i * NTH + tid;            // float4 index over [64][128]
            float4 a = tp[f], p = pp[f];
            a.x += p.x; a.y += p.y; a.z += p.z; a.w += p.w;
            int row = f >> 7;
            int cb  = (f & 127) * 8;          // byte col (4 bf16 = 8B)
            ushort4 q;
            q.x = f2b(a.x); q.y = f2b(a.y); q.z = f2b(a.z); q.w = f2b(a.w);
            *(ushort4*)(sm + xh_off(row, cb)) = q;
        }
    }
    __syncthreads();

    for (int dep = 0; dep < 2; ++dep) {
        // ================= phase A: delta_pre / drive_pre via MFMA =================
        f32x4 accD[2] = {f32x4{0,0,0,0}, f32x4{0,0,0,0}};
        f32x4 accB[2] = {f32x4{0,0,0,0}, f32x4{0,0,0,0}};
        {
            const unsigned short* BdP = pack + (dep * 4 + nt) * 8192;
            const unsigned short* BbP = BdP + BB_OFF;
            const int rowA0 = 32 * mh + lr;
            const int rowA1 = rowA0 + 16;
            #pragma unroll 4
            for (int ks = 0; ks < 16; ++ks) {
                int cb = ks * 64 + lg * 16;
                bf16x8 a0 = *(const bf16x8*)(sm + xh_off(rowA0, cb));
                bf16x8 a1 = *(const bf16x8*)(sm + xh_off(rowA1, cb));
                bf16x8 b0 = *(const bf16x8*)(BdP + ks * 512 + lane * 8);
                bf16x8 b1 = *(const bf16x8*)(BbP + ks * 512 + lane * 8);
                accD[0] = __builtin_amdgcn_mfma_f32_16x16x32_bf16(a0, b0, accD[0], 0, 0, 0);
                accD[1] = __builtin_amdgcn_mfma_f32_16x16x32_bf16(a1, b0, accD[1], 0, 0, 0);
                accB[0] = __builtin_amdgcn_mfma_f32_16x16x32_bf16(a0, b1, accB[0], 0, 0, 0);
                accB[1] = __builtin_amdgcn_mfma_f32_16x16x32_bf16(a1, b1, accB[1], 0, 0, 0);
            }
        }
        // elementwise -> decay/drive in registers
        const int scol = nt * 16 + lr;
        float dcy[8], u[8];
        {
            float bdv = bd[dep * 64 + scol];
            float bbv = bb[dep * 64 + scol];
            float eA  = __expf(A_log[dep * 64 + scol]);
            #pragma unroll
            for (int m = 0; m < 2; ++m)
                #pragma unroll
                for (int r = 0; r < 4; ++r) {
                    float dpre  = accD[m][r] + bdv;
                    float delta = (dpre > 20.f) ? dpre : log1pf(__expf(dpre));
                    dcy[m * 4 + r] = __expf(-delta * eA);
                    u[m * 4 + r]   = delta * (accB[m][r] + bbv);
                }
        }
        // local segment (F,P): chunk c_lo = lg (m=0), c_hi = 4+lg (m=1), 4 t each
        float F[2], P[2];
        #pragma unroll
        for (int m = 0; m < 2; ++m) {
            float h = 0.f, p = 1.f;
            #pragma unroll
            for (int r = 0; r < 4; ++r) { h = fmaf(dcy[m * 4 + r], h, u[m * 4 + r]); p *= dcy[m * 4 + r]; }
            F[m] = h; P[m] = p;
        }
        // ---- intra-wave shuffle-fold over 8 chunks ----
        float hin_lo = 0.f, hin_hi = 0.f;
        if (mh == 0) {
            float hin = 0.f;
            #pragma unroll
            for (int j = 0; j < 8; ++j) {
                float Fj = __shfl(j < 4 ? F[0] : F[1], (j & 3) * 16 + lr, 64);
                float Pj = __shfl(j < 4 ? P[0] : P[1], (j & 3) * 16 + lr, 64);
                if (j == lg)     hin_lo = hin;
                if (j == 4 + lg) hin_hi = hin;
                hin = fmaf(Pj, hin, Fj);
            }
            if (lg == 0) scanF[scol] = hin;   // h at t=31 for this column
        }
        __syncthreads();
        if (mh == 1) {
            float hin = scanF[scol];
            #pragma unroll
            for (int j = 0; j < 8; ++j) {
                float Fj = __shfl(j < 4 ? F[0] : F[1], (j & 3) * 16 + lr, 64);
                float Pj = __shfl(j < 4 ? P[0] : P[1], (j & 3) * 16 + lr, 64);
                if (j == lg)     hin_lo = hin;
                if (j == 4 + lg) hin_hi = hin;
                hin = fmaf(Pj, hin, Fj);
            }
        }
        // ---- apply + write hs (bf16, swizzled) ----
        #pragma unroll
        for (int m = 0; m < 2; ++m) {
            float h = m ? hin_hi : hin_lo;
            #pragma unroll
            for (int r = 0; r < 4; ++r) {
                h = fmaf(dcy[m * 4 + r], h, u[m * 4 + r]);
                int t = 32 * mh + 16 * m + 4 * lg + r;
                *(unsigned short*)(sm + HS_B + hs_off(t, scol * 2)) = f2b(h);
            }
            if (m == 1 && mh == 1 && lg == 3) hT[scol] = h;   // t = 63
        }
        __syncthreads();

        // ================= shot-term: stm[d] = bs + hT @ Ws =================
        {
            const float* Wsd = Ws + dep * (NS * ND);
            float acc = bs[dep * ND + tid];
            #pragma unroll 8
            for (int s = 0; s < 64; ++s) acc = fmaf(hT[s], Wsd[s * ND + tid], acc);
            stm[tid] = acc;
        }

        // ================= phase C: hidden = hs@Wc + bc + x*Dp + stm =================
        f32x4 accC[4][4];
        #pragma unroll
        for (int m = 0; m < 4; ++m)
            #pragma unroll
            for (int n = 0; n < 4; ++n) accC[m][n] = f32x4{0, 0, 0, 0};
        {
            const unsigned short* BcP = pack + BC_OFF + (dep * 32 + w * 4) * 1024;
            #pragma unroll
            for (int ks = 0; ks < 2; ++ks) {
                bf16x8 a[4];
                #pragma unroll
                for (int m = 0; m < 4; ++m)
                    a[m] = *(const bf16x8*)(sm + HS_B + hs_off(m * 16 + lr, ks * 64 + lg * 16));
                #pragma unroll
                for (int n = 0; n < 4; ++n) {
                    bf16x8 bfr = *(const bf16x8*)(BcP + (n * 2 + ks) * 512 + lane * 8);
                    #pragma unroll
                    for (int m = 0; m < 4; ++m)
                        accC[m][n] = __builtin_amdgcn_mfma_f32_16x16x32_bf16(a[m], bfr, accC[m][n], 0, 0, 0);
                }
            }
        }
        __syncthreads();   // stm ready; hs reads done

        // epilogue
        {
            const float* bcd = bc + dep * ND;
            const float* Dpd = Dp + dep * ND;
            #pragma unroll
            for (int n = 0; n < 4; ++n) {
                int d = w * 64 + n * 16 + lr;
                float bcv = bcd[d], dpv = Dpd[d], stv = stm[d];
                float psum = 0.f;
                #pragma unroll
                for (int m = 0; m < 4; ++m)
                    #pragma unroll
                    for (int r = 0; r < 4; ++r) {
                        int t = m * 16 + 4 * lg + r;
                        float x = b2f(*(const unsigned short*)(sm + xh_off(t, d * 2)));
                        float v = accC[m][n][r] + bcv + x * dpv + stv;
                        if (dep == 0) {
                            *(unsigned short*)(sm + xh_off(t, d * 2)) = f2b(v);
                        } else {
                            out_hidden[((size_t)b * NT + t) * ND + d] = v;
                            psum += v;
                        }
                    }
                if (dep == 1) {
                    psum += __shfl_xor(psum, 16, 64);
                    psum += __shfl_xor(psum, 32, 64);
                    if (lg == 0) stm[d] = psum * (1.f / 64.f) + stv;   // pooled + shot-term
                }
            }
        }
        __syncthreads();
    } // depth

    // ================= LayerNorm on pooled (in stm) =================
    float pv = stm[tid];
    float s1 = pv, s2 = pv * pv;
    #pragma unroll
    for (int off = 32; off; off >>= 1) {
        s1 += __shfl_down(s1, off, 64);
        s2 += __shfl_down(s2, off, 64);
    }
    if (lane == 0) { red[w] = s1; red[8 + w] = s2; }
    __syncthreads();
    if (tid == 0) {
        float a = 0.f, q = 0.f;
        for (int i = 0; i < 8; ++i) { a += red[i]; q += red[8 + i]; }
        float mu = a * (1.0f / ND);
        float var = q * (1.0f / ND) - mu * mu;
        red[16] = mu;
        red[17] = rsqrtf(var + LN_EPS);
    }
    __syncthreads();
    out_shot[(size_t)b * ND + tid] = (pv - red[16]) * red[17] * gma[tid] + bta[tid];
}

extern "C" void kernel_launch(void* const* d_in, const int* in_sizes, int n_in,
                              void* d_out, int out_size, void* d_ws, size_t ws_size,
                              hipStream_t stream) {
    const float* tokens  = (const float*)d_in[0];
    const float* pos_emb = (const float*)d_in[1];
    const float* A_log   = (const float*)d_in[2];
    const float* Wd      = (const float*)d_in[3];
    const float* bd      = (const float*)d_in[4];
    const float* Wb      = (const float*)d_in[5];
    const float* bb      = (const float*)d_in[6];
    const float* Wc      = (const float*)d_in[7];
    const float* bc      = (const float*)d_in[8];
    const float* Dp      = (const float*)d_in[9];
    const float* Ws      = (const float*)d_in[10];
    const float* bs      = (const float*)d_in[11];
    const float* gma     = (const float*)d_in[12];
    const float* bta     = (const float*)d_in[13];

    unsigned short* pack = (unsigned short*)d_ws;   // 393216 B needed
    float* out_hidden = (float*)d_out;
    float* out_shot   = (float*)d_out + (size_t)NB * NT * ND;

    prep_pack<<<(PACK_ELEMS + 255) / 256, 256, 0, stream>>>(Wd, Wb, Wc, pack);

    hipFuncSetAttribute((const void*)ssm_mfma,
                        hipFuncAttributeMaxDynamicSharedMemorySize,
                        (int)LDS_BYTES);
    ssm_mfma<<<NB, NTH, LDS_BYTES, stream>>>(
        tokens, pos_emb, A_log, bd, bb, bc, Dp, Ws, bs, gma, bta,
        pack, out_hidden, out_shot);
}